// Round 6
// baseline (7391.217 us; speedup 1.0000x reference)
//
#include <hip/hip_runtime.h>
#include <stdint.h>

// ---------------------------------------------------------------------------
// SNN categorical policy forward (B=1024, C_IN=8, HID=300, OUT=2, T=300)
//
// R6: R4's register-window FIR + the actual spill fix.
//  Root cause of R3/R4/R5's 256-VGPR + GB-scale scratch: full unrolling makes
//  kD[j] compile-time-indexed LDS loads that are loop-invariant across the
//  tb-loop; LICM hoists ~99 f64 taps into ~198 registers. Fix: read taps via
//  a VOLATILE LDS pointer (unhoistable, ~5 live at a time), forbid tb-loop
//  unrolling, sched_barrier per tap group.
//  Numerics identical to verified R2-R5: x via bitmask-selected f32 add chain
//  (R5-verified), FIR f64 j-ascending with f32-rounded taps, exact f32 scan.
//  K2: unchanged (verified bit-exact).
// ---------------------------------------------------------------------------

#define NB    1024
#define CIN   8
#define HID   300
#define TLEN  300
#define KTAP  99
#define THETA 10.0f
#define TB    10

__device__ __forceinline__ void threefry2x32(uint32_t c0, uint32_t c1,
                                             uint32_t& o0, uint32_t& o1) {
  const uint32_t k0 = 0u, k1 = 42u;
  const uint32_t k2 = k0 ^ k1 ^ 0x1BD11BDAu;
  uint32_t x0 = c0 + k0, x1 = c1 + k1;
#define TFR(r) { x0 += x1; x1 = (x1 << (r)) | (x1 >> (32 - (r))); x1 ^= x0; }
  TFR(13) TFR(15) TFR(26) TFR(6)  x0 += k1; x1 += k2 + 1u;
  TFR(17) TFR(29) TFR(16) TFR(24) x0 += k2; x1 += k0 + 2u;
  TFR(13) TFR(15) TFR(26) TFR(6)  x0 += k0; x1 += k1 + 3u;
  TFR(17) TFR(29) TFR(16) TFR(24) x0 += k1; x1 += k2 + 4u;
  TFR(13) TFR(15) TFR(26) TFR(6)  x0 += k2; x1 += k0 + 5u;
#undef TFR
  o0 = x0; o1 = x1;
}

__device__ __forceinline__ float jax_uniform_from_bits(uint32_t bits) {
  uint32_t fb = (bits >> 9) | 0x3F800000u;
  float f = __uint_as_float(fb) - 1.0f;
  const float tiny = 1.17549435e-38f;
  float u = __fadd_rn(f, tiny);
  return fmaxf(tiny, u);
}

// ======================= Kernel 1: layer-1 SNN ============================
__global__ __launch_bounds__(64, 1)
void snn_l1_kernel(const float* __restrict__ enc,
                   const float* __restrict__ W1,
                   unsigned long long* __restrict__ maskG) {
  __shared__ double   kD[100];
  __shared__ uint32_t encB[TLEN];

  const int lane = threadIdx.x;
  const int bh   = blockIdx.x;          // h-chunk [0,5)
  const int b    = blockIdx.y;
  const int h    = bh * 64 + lane;

  // taps: identical formula to verified R2-R5 kernels
  for (int j = lane; j < 100; j += 64) {
    float q  = (float)j / 10.0f;
    float ef = (float)exp((double)(1.0f - q));
    kD[j] = (double)__fmul_rn(q, ef);
  }
  // pack enc bits (enc values are exactly 0.0f or 1.0f) — R5-verified
  for (int t = lane; t < TLEN; t += 64) {
    uint32_t m = 0u;
#pragma unroll
    for (int c = 0; c < CIN; ++c)
      if (enc[b * (CIN * TLEN) + c * TLEN + t] != 0.0f) m |= (1u << c);
    encB[t] = m;
  }
  __syncthreads();

  float w1f[8];
#pragma unroll
  for (int c = 0; c < 8; ++c)
    w1f[c] = (h < HID) ? W1[h * 8 + c] : 0.0f;

  const float arf = (float)0.6065306597126334;   // f32(exp(-0.5))
  const float Af  = (float)-27.182818284590452;  // f32(-10e)

  // volatile view of the taps: loads cannot be hoisted by LICM (the R3-R5
  // spill source: ~99 hoisted f64 taps = ~198 VGPRs).
  volatile const double* kDv = kD;

  float W[99 + TB];
#pragma unroll
  for (int m = 0; m < 99 + TB; ++m) W[m] = 0.0f;

  float RX = 0.0f, RY = 0.0f;
  unsigned long long* mptr = maskG + b * (TLEN * 5) + bh;

#pragma clang loop unroll(disable)
  for (int tb = 0; tb < TLEN / TB; ++tb) {
    const int t0 = tb * TB;

    // ---- phase 1: x[t0..t0+9] via bitmask add chain (bit-identical) ----
#pragma unroll
    for (int i = 0; i < TB; ++i) {
      const uint32_t bits = encB[t0 + i];
      float xf = 0.0f;
#pragma unroll
      for (int c = 0; c < 8; ++c) {
        float wsel = (bits & (1u << c)) ? w1f[c] : 0.0f;
        xf = __fadd_rn(xf, wsel);
      }
      W[99 + i] = xf;
    }
    __builtin_amdgcn_sched_barrier(0);

    // ---- phase 2: FIR, tap groups of 5, f64, j ascending (canonical) ----
    double acc[TB];
#pragma unroll
    for (int i = 0; i < TB; ++i) acc[i] = 0.0;

#pragma unroll
    for (int g = 0; g < 20; ++g) {
      const int jlo = 5 * g + 1;
      const int jhi = (5 * g + 5 < 99) ? (5 * g + 5) : 99;
      const int nw  = (jhi - jlo) + TB;            // 14 (13 for g=19)
      double X64[14];
#pragma unroll
      for (int m = 0; m < nw; ++m)
        X64[m] = (double)W[99 - jhi + m];          // = x[t0 - jhi + m]
#pragma unroll
      for (int j = jlo; j <= jhi; ++j) {
        const double kk = kDv[j];                  // volatile: per-use ds_read
#pragma unroll
        for (int i = 0; i < TB; ++i)
          acc[i] += kk * X64[i + (jhi - j)];       // x[t0 + i - j]
      }
      __builtin_amdgcn_sched_barrier(0);
    }

    // ---- phase 3: spike scan (exact f32 order, verified) ----
#pragma unroll
    for (int i = 0; i < TB; ++i) {
      float umem = (float)acc[i];
      float v  = __fsub_rn(__fadd_rn(umem, RX), THETA);
      bool  sp = (v >= 0.0f) && (h < HID);
      unsigned long long bal = __ballot(sp);
      if (lane == 0) mptr[(t0 + i) * 5] = bal;
      float sf = sp ? 1.0f : 0.0f;
      float y2 = __fadd_rn(RY, __fmul_rn(Af, sf));
      RX = __fmul_rn(arf, __fadd_rn(RX, y2));
      RY = __fmul_rn(arf, y2);
    }
    __builtin_amdgcn_sched_barrier(0);

    // ---- phase 4: slide window by TB ----
#pragma unroll
    for (int m = 0; m < 99; ++m) W[m] = W[m + TB];
    __builtin_amdgcn_sched_barrier(0);
  }
}

// ================== Kernel 2: layer-2 + head (per b) ======================
__global__ __launch_bounds__(320)
void snn_l2_kernel(const float* __restrict__ W2,
                   const unsigned long long* __restrict__ maskG,
                   float* __restrict__ out) {
  __shared__ double             kD[100];
  __shared__ double             W2D[2 * HID];
  __shared__ unsigned long long maskL[TLEN * 5];
  __shared__ double             zD[2 * 304];
  __shared__ float              u2L[2 * 304];
  __shared__ float              lgL[2];

  const int tid = threadIdx.x;
  const int b   = blockIdx.x;

  const float arf = (float)0.6065306597126334;
  const float Af  = (float)-27.182818284590452;

  for (int j = tid; j < 100; j += 320) {
    float q  = (float)j / 10.0f;
    float ef = (float)exp((double)(1.0f - q));
    kD[j] = (double)__fmul_rn(q, ef);
  }
  for (int i = tid; i < 2 * HID; i += 320)
    W2D[i] = (double)W2[i];
  for (int i = tid; i < TLEN * 5; i += 320)
    maskL[i] = maskG[(size_t)b * (TLEN * 5) + i];
  __syncthreads();

  // ---- fc2: flat ascending-h f64 chain, branchless (bit-identical) ----
  if (tid < TLEN) {
    const int t = tid;
    double z0 = 0.0, z1 = 0.0;
#pragma unroll
    for (int w5 = 0; w5 < 5; ++w5) {
      const unsigned long long mm = maskL[t * 5 + w5];
      const int kend = (w5 == 4) ? (HID - 256) : 64;
      for (int k = 0; k < kend; ++k) {
        const bool bit = (mm >> k) & 1ull;
        const int  hh  = w5 * 64 + k;
        z0 += bit ? W2D[hh] : 0.0;
        z1 += bit ? W2D[HID + hh] : 0.0;
      }
    }
    zD[t]       = (double)((float)z0);   // f32-rounded at tensor boundary
    zD[304 + t] = (double)((float)z1);
  }
  __syncthreads();

  // ---- psp2 (f64 accumulate, j ascending) ----
  if (tid < TLEN) {
    const int t = tid;
    double a0 = 0.0, a1 = 0.0;
    const int jmax = (t < KTAP) ? t : KTAP;
    for (int j = 1; j <= jmax; ++j) {
      const double kk = kD[j];
      a0 += kk * zD[t - j];
      a1 += kk * zD[304 + t - j];
    }
    u2L[t]       = (float)a0;
    u2L[304 + t] = (float)a1;
  }
  __syncthreads();

  // ---- layer-2 spike scan + count ----
  if (tid < 2) {
    float RX = 0.0f, RY = 0.0f;
    int cnt = 0;
    for (int t = 0; t < TLEN; ++t) {
      float u  = u2L[tid * 304 + t];
      float v  = __fsub_rn(__fadd_rn(u, RX), THETA);
      bool  sp = (v >= 0.0f);
      cnt += sp ? 1 : 0;
      float sf = sp ? 1.0f : 0.0f;
      float y2 = __fadd_rn(RY, __fmul_rn(Af, sf));
      RX = __fmul_rn(arf, __fadd_rn(RX, y2));
      RY = __fmul_rn(arf, y2);
    }
    lgL[tid] = (float)cnt;
  }
  __syncthreads();

  // ---- head (verified) ----
  if (tid == 0) {
    float l0 = lgL[0], l1 = lgL[1];
    uint32_t o0, o1;
    threefry2x32(0u, 2u * (uint32_t)b, o0, o1);
    float g0 = -logf(-logf(jax_uniform_from_bits(o0 ^ o1)));
    threefry2x32(0u, 2u * (uint32_t)b + 1u, o0, o1);
    float g1 = -logf(-logf(jax_uniform_from_bits(o0 ^ o1)));

    float v0 = __fadd_rn(l0, g0);
    float v1 = __fadd_rn(l1, g1);
    int   pi = (v1 > v0) ? 1 : 0;
    float m   = fmaxf(l0, l1);
    float s0f = __fsub_rn(l0, m), s1f = __fsub_rn(l1, m);
    float lse = logf(__fadd_rn(expf(s0f), expf(s1f)));
    float lp  = __fsub_rn(pi ? s1f : s0f, lse);

    out[2 * b + 0] = l0;
    out[2 * b + 1] = l1;
    out[2048 + b]  = (float)pi;
    out[3072 + b]  = lp;
  }
}

extern "C" void kernel_launch(void* const* d_in, const int* in_sizes, int n_in,
                              void* d_out, int out_size, void* d_ws, size_t ws_size,
                              hipStream_t stream) {
  const float* enc = (const float*)d_in[0];
  const float* W1  = (const float*)d_in[1];
  const float* W2  = (const float*)d_in[2];
  float* out = (float*)d_out;

  unsigned long long* maskG = (unsigned long long*)d_ws;  // 12.3 MB

  snn_l1_kernel<<<dim3(5, NB), dim3(64), 0, stream>>>(enc, W1, maskG);
  snn_l2_kernel<<<dim3(NB), dim3(320), 0, stream>>>(W2, maskG, out);
}

// Round 7
// 1649.655 us; speedup vs baseline: 4.4805x; 4.4805x over previous
//
#include <hip/hip_runtime.h>
#include <stdint.h>

// ---------------------------------------------------------------------------
// SNN categorical policy forward (B=1024, C_IN=8, HID=300, OUT=2, T=300)
//
// R7: t-parallel FIR, state-free threads (kills the R3-R6 spill class).
//  K1: grid (5 bh, 1024 b), 512 threads (8 waves), lane = h.
//    A: x[t][lane] -> LDS xbuf[399][64] (99 zero pad slots; bit-select
//       f32 add chain, R5-verified bit-identical).
//    B: wave-parallel over 4-t chunks; per chunk 4 f64 accs, runtime s-loop
//       (s descending == j ascending 1..99 => canonical verified sum order);
//       zero-padded taps kpad[105] make out-of-range terms exact +0.
//       Thread live state ~8 f64 -> no spill possible by construction.
//    C: wave 0 runs the exact-f32 spike scan (RX/RY in regs across halves),
//       ballot masks -> d_ws. u buffered in halves (152/148) to fit LDS.
//  K2: unchanged (verified bit-exact since R2).
// ---------------------------------------------------------------------------

#define NB    1024
#define CIN   8
#define HID   300
#define TLEN  300
#define KTAP  99
#define THETA 10.0f
#define HALF1 152

// LDS layout (bytes):
//  kpad  double[105]        [0,      840)
//  xbuf  float[399*64]      [840,    102984)   s in [-99, 299] at slot 99+s
//  ubuf  float[152*64]      [102984, 141896)
//  encB  uint32[300]        [141896, 143096)
#define LDS_K1 143104

__device__ __forceinline__ void threefry2x32(uint32_t c0, uint32_t c1,
                                             uint32_t& o0, uint32_t& o1) {
  const uint32_t k0 = 0u, k1 = 42u;
  const uint32_t k2 = k0 ^ k1 ^ 0x1BD11BDAu;
  uint32_t x0 = c0 + k0, x1 = c1 + k1;
#define TFR(r) { x0 += x1; x1 = (x1 << (r)) | (x1 >> (32 - (r))); x1 ^= x0; }
  TFR(13) TFR(15) TFR(26) TFR(6)  x0 += k1; x1 += k2 + 1u;
  TFR(17) TFR(29) TFR(16) TFR(24) x0 += k2; x1 += k0 + 2u;
  TFR(13) TFR(15) TFR(26) TFR(6)  x0 += k0; x1 += k1 + 3u;
  TFR(17) TFR(29) TFR(16) TFR(24) x0 += k1; x1 += k2 + 4u;
  TFR(13) TFR(15) TFR(26) TFR(6)  x0 += k2; x1 += k0 + 5u;
#undef TFR
  o0 = x0; o1 = x1;
}

__device__ __forceinline__ float jax_uniform_from_bits(uint32_t bits) {
  uint32_t fb = (bits >> 9) | 0x3F800000u;
  float f = __uint_as_float(fb) - 1.0f;
  const float tiny = 1.17549435e-38f;
  float u = __fadd_rn(f, tiny);
  return fmaxf(tiny, u);
}

// ======================= Kernel 1: layer-1 SNN ============================
__global__ __launch_bounds__(512, 1)
void snn_l1_kernel(const float* __restrict__ enc,
                   const float* __restrict__ W1,
                   unsigned long long* __restrict__ maskG) {
  extern __shared__ char smem[];
  double*   kpad = (double*)(smem);             // kpad[j+2] = kD[j], 0 outside [1,99]
  float*    xbuf = (float*)(smem + 840);
  float*    ubuf = (float*)(smem + 102984);
  uint32_t* encB = (uint32_t*)(smem + 141896);

  const int tid  = threadIdx.x;
  const int lane = tid & 63;
  const int wv   = tid >> 6;            // wave id 0..7
  const int bh   = blockIdx.x;          // h-chunk [0,5)
  const int b    = blockIdx.y;
  const int h    = bh * 64 + lane;

  // taps (identical formula to verified R2-R6), zero-padded
  for (int i = tid; i < 105; i += 512) {
    const int j = i - 2;
    double v = 0.0;
    if (j >= 1 && j <= KTAP) {
      float q  = (float)j / 10.0f;
      float ef = (float)exp((double)(1.0f - q));
      v = (double)__fmul_rn(q, ef);
    }
    kpad[i] = v;
  }
  // pack enc bits (enc is exactly 0.0f/1.0f) — R5-verified
  for (int t = tid; t < TLEN; t += 512) {
    uint32_t m = 0u;
#pragma unroll
    for (int c = 0; c < CIN; ++c)
      if (enc[b * (CIN * TLEN) + c * TLEN + t] != 0.0f) m |= (1u << c);
    encB[t] = m;
  }
  // zero history slots s in [-99,-1]
  for (int i = tid; i < 99 * 64; i += 512)
    xbuf[i] = 0.0f;
  __syncthreads();

  float w1f[8];
#pragma unroll
  for (int c = 0; c < 8; ++c)
    w1f[c] = (h < HID) ? W1[h * 8 + c] : 0.0f;

  // ---- phase A: fill x[t][lane] (bit-identical f32 add chain) ----
  for (int t = wv; t < TLEN; t += 8) {
    const uint32_t bits = encB[t];
    float xf = 0.0f;
#pragma unroll
    for (int c = 0; c < 8; ++c) {
      float wsel = (bits & (1u << c)) ? w1f[c] : 0.0f;
      xf = __fadd_rn(xf, wsel);
    }
    xbuf[(99 + t) * 64 + lane] = xf;
  }
  __syncthreads();

  // ---- phase B: FIR for a half-range of t, 4 outputs per wave-chunk ----
  auto fir_half = [&](int tbeg, int tend) {
    const int nchunk = (tend - tbeg) >> 2;
    for (int c = wv; c < nchunk; c += 8) {
      const int t0 = tbeg + c * 4;
      double a0 = 0.0, a1 = 0.0, a2 = 0.0, a3 = 0.0;
      // s descending == j ascending (canonical order); pad terms exact +0
      const float* xp = xbuf + lane;
#pragma clang loop unroll_count(2)
      for (int s = t0 + 2; s >= t0 - KTAP; --s) {
        const double xv = (double)xp[(99 + s) * 64];
        const int m = (t0 - s) + 2;               // j+2 for acc0
        a0 += kpad[m + 0] * xv;
        a1 += kpad[m + 1] * xv;
        a2 += kpad[m + 2] * xv;
        a3 += kpad[m + 3] * xv;
      }
      const int ub = (t0 - tbeg) * 64 + lane;
      ubuf[ub + 0 * 64] = (float)a0;
      ubuf[ub + 1 * 64] = (float)a1;
      ubuf[ub + 2 * 64] = (float)a2;
      ubuf[ub + 3 * 64] = (float)a3;
    }
  };

  // ---- phase C state (wave 0 only, persists across halves) ----
  const float arf = (float)0.6065306597126334;   // f32(exp(-0.5))
  const float Af  = (float)-27.182818284590452;  // f32(-10e)
  float RX = 0.0f, RY = 0.0f;
  unsigned long long* mptr = maskG + b * (TLEN * 5) + bh;

  // half 1
  fir_half(0, HALF1);
  __syncthreads();
  if (wv == 0) {
    for (int t = 0; t < HALF1; ++t) {
      float umem = ubuf[t * 64 + lane];
      float v  = __fsub_rn(__fadd_rn(umem, RX), THETA);
      bool  sp = (v >= 0.0f) && (h < HID);
      unsigned long long bal = __ballot(sp);
      if (lane == 0) mptr[t * 5] = bal;
      float sf = sp ? 1.0f : 0.0f;
      float y2 = __fadd_rn(RY, __fmul_rn(Af, sf));
      RX = __fmul_rn(arf, __fadd_rn(RX, y2));
      RY = __fmul_rn(arf, y2);
    }
  }
  __syncthreads();        // ubuf free for half 2

  // half 2
  fir_half(HALF1, TLEN);
  __syncthreads();
  if (wv == 0) {
    for (int t = HALF1; t < TLEN; ++t) {
      float umem = ubuf[(t - HALF1) * 64 + lane];
      float v  = __fsub_rn(__fadd_rn(umem, RX), THETA);
      bool  sp = (v >= 0.0f) && (h < HID);
      unsigned long long bal = __ballot(sp);
      if (lane == 0) mptr[t * 5] = bal;
      float sf = sp ? 1.0f : 0.0f;
      float y2 = __fadd_rn(RY, __fmul_rn(Af, sf));
      RX = __fmul_rn(arf, __fadd_rn(RX, y2));
      RY = __fmul_rn(arf, y2);
    }
  }
}

// ================== Kernel 2: layer-2 + head (per b) ======================
__global__ __launch_bounds__(320)
void snn_l2_kernel(const float* __restrict__ W2,
                   const unsigned long long* __restrict__ maskG,
                   float* __restrict__ out) {
  __shared__ double             kD[100];
  __shared__ double             W2D[2 * HID];
  __shared__ unsigned long long maskL[TLEN * 5];
  __shared__ double             zD[2 * 304];
  __shared__ float              u2L[2 * 304];
  __shared__ float              lgL[2];

  const int tid = threadIdx.x;
  const int b   = blockIdx.x;

  const float arf = (float)0.6065306597126334;
  const float Af  = (float)-27.182818284590452;

  for (int j = tid; j < 100; j += 320) {
    float q  = (float)j / 10.0f;
    float ef = (float)exp((double)(1.0f - q));
    kD[j] = (double)__fmul_rn(q, ef);
  }
  for (int i = tid; i < 2 * HID; i += 320)
    W2D[i] = (double)W2[i];
  for (int i = tid; i < TLEN * 5; i += 320)
    maskL[i] = maskG[(size_t)b * (TLEN * 5) + i];
  __syncthreads();

  // ---- fc2: flat ascending-h f64 chain, branchless (bit-identical) ----
  if (tid < TLEN) {
    const int t = tid;
    double z0 = 0.0, z1 = 0.0;
#pragma unroll
    for (int w5 = 0; w5 < 5; ++w5) {
      const unsigned long long mm = maskL[t * 5 + w5];
      const int kend = (w5 == 4) ? (HID - 256) : 64;
      for (int k = 0; k < kend; ++k) {
        const bool bit = (mm >> k) & 1ull;
        const int  hh  = w5 * 64 + k;
        z0 += bit ? W2D[hh] : 0.0;
        z1 += bit ? W2D[HID + hh] : 0.0;
      }
    }
    zD[t]       = (double)((float)z0);   // f32-rounded at tensor boundary
    zD[304 + t] = (double)((float)z1);
  }
  __syncthreads();

  // ---- psp2 (f64 accumulate, j ascending) ----
  if (tid < TLEN) {
    const int t = tid;
    double a0 = 0.0, a1 = 0.0;
    const int jmax = (t < KTAP) ? t : KTAP;
    for (int j = 1; j <= jmax; ++j) {
      const double kk = kD[j];
      a0 += kk * zD[t - j];
      a1 += kk * zD[304 + t - j];
    }
    u2L[t]       = (float)a0;
    u2L[304 + t] = (float)a1;
  }
  __syncthreads();

  // ---- layer-2 spike scan + count ----
  if (tid < 2) {
    float RX = 0.0f, RY = 0.0f;
    int cnt = 0;
    for (int t = 0; t < TLEN; ++t) {
      float u  = u2L[tid * 304 + t];
      float v  = __fsub_rn(__fadd_rn(u, RX), THETA);
      bool  sp = (v >= 0.0f);
      cnt += sp ? 1 : 0;
      float sf = sp ? 1.0f : 0.0f;
      float y2 = __fadd_rn(RY, __fmul_rn(Af, sf));
      RX = __fmul_rn(arf, __fadd_rn(RX, y2));
      RY = __fmul_rn(arf, y2);
    }
    lgL[tid] = (float)cnt;
  }
  __syncthreads();

  // ---- head (verified) ----
  if (tid == 0) {
    float l0 = lgL[0], l1 = lgL[1];
    uint32_t o0, o1;
    threefry2x32(0u, 2u * (uint32_t)b, o0, o1);
    float g0 = -logf(-logf(jax_uniform_from_bits(o0 ^ o1)));
    threefry2x32(0u, 2u * (uint32_t)b + 1u, o0, o1);
    float g1 = -logf(-logf(jax_uniform_from_bits(o0 ^ o1)));

    float v0 = __fadd_rn(l0, g0);
    float v1 = __fadd_rn(l1, g1);
    int   pi = (v1 > v0) ? 1 : 0;
    float m   = fmaxf(l0, l1);
    float s0f = __fsub_rn(l0, m), s1f = __fsub_rn(l1, m);
    float lse = logf(__fadd_rn(expf(s0f), expf(s1f)));
    float lp  = __fsub_rn(pi ? s1f : s0f, lse);

    out[2 * b + 0] = l0;
    out[2 * b + 1] = l1;
    out[2048 + b]  = (float)pi;
    out[3072 + b]  = lp;
  }
}

extern "C" void kernel_launch(void* const* d_in, const int* in_sizes, int n_in,
                              void* d_out, int out_size, void* d_ws, size_t ws_size,
                              hipStream_t stream) {
  const float* enc = (const float*)d_in[0];
  const float* W1  = (const float*)d_in[1];
  const float* W2  = (const float*)d_in[2];
  float* out = (float*)d_out;

  unsigned long long* maskG = (unsigned long long*)d_ws;  // 12.3 MB

  hipFuncSetAttribute((const void*)snn_l1_kernel,
                      hipFuncAttributeMaxDynamicSharedMemorySize, LDS_K1);

  snn_l1_kernel<<<dim3(5, NB), dim3(512), LDS_K1, stream>>>(enc, W1, maskG);
  snn_l2_kernel<<<dim3(NB), dim3(320), 0, stream>>>(W2, maskG, out);
}

// Round 8
// 795.879 us; speedup vs baseline: 9.2869x; 2.0727x over previous
//
#include <hip/hip_runtime.h>
#include <stdint.h>

// ---------------------------------------------------------------------------
// SNN categorical policy forward (B=1024, C_IN=8, HID=300, OUT=2, T=300)
//
// R8: t-parallel FIR (state-free, spill-proof as R7) + throughput fixes:
//  - 1024 threads (16 waves) per block -> 4 waves/SIMD.
//  - inner loop: 8-deep s-unroll; 8 LDS x-reads + 11 SCALAR tap loads
//    (taps in global buffer from init kernel; uniform index via
//    readfirstlane -> s_load, SGPR-resident, no LICM pressure) per 32 f64 FMA.
//  - quarter-pipelined scan: wave 0 scans quarter q (double-buffered ubuf)
//    while waves 1-15 compute quarter q+1 -> serial scan hidden.
//  - mask layout [b][5][300]: contiguous per-block stores (R7 wrote 48 MB
//    for 12.3 MB of masks due to strided 8B stores).
// Numerics identical to verified R2-R7: x bit-select f32 add chain, FIR f64
// j-ascending with f32-rounded taps (pad terms exact +/-0 no-ops), exact-f32
// spike scan, fc2 f64 chain, partitionable threefry head.
// ---------------------------------------------------------------------------

#define NB    1024
#define CIN   8
#define HID   300
#define TLEN  300
#define KTAP  99
#define THETA 10.0f
#define QMAX  76

// K1 LDS layout (bytes):
//  xbuf float[401*64]   [0,      102656)   slot = 101 + s, s in [-101, 299]
//  ubuf float[2*76*64]  [102656, 141568)
//  encB uint32[300]     [141568, 142768)
#define LDS_K1 142768

__device__ __forceinline__ void threefry2x32(uint32_t c0, uint32_t c1,
                                             uint32_t& o0, uint32_t& o1) {
  const uint32_t k0 = 0u, k1 = 42u;
  const uint32_t k2 = k0 ^ k1 ^ 0x1BD11BDAu;
  uint32_t x0 = c0 + k0, x1 = c1 + k1;
#define TFR(r) { x0 += x1; x1 = (x1 << (r)) | (x1 >> (32 - (r))); x1 ^= x0; }
  TFR(13) TFR(15) TFR(26) TFR(6)  x0 += k1; x1 += k2 + 1u;
  TFR(17) TFR(29) TFR(16) TFR(24) x0 += k2; x1 += k0 + 2u;
  TFR(13) TFR(15) TFR(26) TFR(6)  x0 += k0; x1 += k1 + 3u;
  TFR(17) TFR(29) TFR(16) TFR(24) x0 += k1; x1 += k2 + 4u;
  TFR(13) TFR(15) TFR(26) TFR(6)  x0 += k2; x1 += k0 + 5u;
#undef TFR
  o0 = x0; o1 = x1;
}

__device__ __forceinline__ float jax_uniform_from_bits(uint32_t bits) {
  uint32_t fb = (bits >> 9) | 0x3F800000u;
  float f = __uint_as_float(fb) - 1.0f;
  const float tiny = 1.17549435e-38f;
  float u = __fadd_rn(f, tiny);
  return fmaxf(tiny, u);
}

// ==================== Kernel 0: taps -> global (scalar-loadable) ==========
__global__ void snn_taps_kernel(double* __restrict__ tapsG) {
  const int i = threadIdx.x;
  if (i < 107) {
    const int j = i - 2;                 // tapsG[j+2] = kD[j], 0 outside [1,99]
    double v = 0.0;
    if (j >= 1 && j <= KTAP) {
      float q  = (float)j / 10.0f;
      float ef = (float)exp((double)(1.0f - q));   // same formula as R2-R7
      v = (double)__fmul_rn(q, ef);
    }
    tapsG[i] = v;
  }
}

// ======================= Kernel 1: layer-1 SNN ============================
__global__ __launch_bounds__(1024, 1)
void snn_l1_kernel(const float* __restrict__ enc,
                   const float* __restrict__ W1,
                   const double* __restrict__ tapsG,
                   unsigned long long* __restrict__ maskG) {
  extern __shared__ char smem[];
  float*    xbuf = (float*)(smem);
  float*    ubuf = (float*)(smem + 102656);
  uint32_t* encB = (uint32_t*)(smem + 141568);

  const int tid  = threadIdx.x;
  const int lane = tid & 63;
  const int wv   = tid >> 6;            // wave 0..15
  const int bh   = blockIdx.x;          // h-chunk [0,5)
  const int b    = blockIdx.y;
  const int h    = bh * 64 + lane;

  // pack enc bits (enc is exactly 0.0f/1.0f) — R5-verified bit-identical
  if (tid < TLEN) {
    uint32_t m = 0u;
#pragma unroll
    for (int c = 0; c < CIN; ++c)
      if (enc[b * (CIN * TLEN) + c * TLEN + tid] != 0.0f) m |= (1u << c);
    encB[tid] = m;
  }
  // zero history slots s in [-101,-1] (rows 0..100)
  for (int i = tid; i < 101 * 64; i += 1024)
    xbuf[i] = 0.0f;
  __syncthreads();

  float w1f[8];
#pragma unroll
  for (int c = 0; c < 8; ++c)
    w1f[c] = (h < HID) ? W1[h * 8 + c] : 0.0f;

  // ---- phase A: x[t][lane] (bit-identical f32 add chain) ----
  for (int t = wv; t < TLEN; t += 16) {
    const uint32_t bits = encB[t];
    float xf = 0.0f;
#pragma unroll
    for (int c = 0; c < 8; ++c) {
      float wsel = (bits & (1u << c)) ? w1f[c] : 0.0f;
      xf = __fadd_rn(xf, wsel);
    }
    xbuf[(101 + t) * 64 + lane] = xf;
  }
  __syncthreads();

  const float arf = (float)0.6065306597126334;   // f32(exp(-0.5))
  const float Af  = (float)-27.182818284590452;  // f32(-10e)

  // FIR for chunk range of one quarter. Per output t0+i:
  //   sum over (g asc, d asc) of taps[i+8g+d] * x[t0+2-8g-d]  == j ascending;
  //   j outside [1,99] hits zero taps (exact +/-0 no-ops). Canonical order.
  auto fir_range = [&](int qs, int qlen, int bufsel, int cstart, int cstep) {
    const int nq = qlen >> 2;
#pragma clang loop unroll(disable)
    for (int c = cstart; c < nq; c += cstep) {
      const int t0 = qs + c * 4;
      double a0 = 0.0, a1 = 0.0, a2 = 0.0, a3 = 0.0;
#pragma clang loop unroll(disable)
      for (int g = 0; g < 13; ++g) {
        const int m0 = __builtin_amdgcn_readfirstlane(g << 3);  // scalar taps idx
        const float* xg = xbuf + (96 + t0 - (g << 3)) * 64 + lane;
        float xf[8];
#pragma unroll
        for (int u = 0; u < 8; ++u) xf[u] = xg[u * 64];          // s asc
        double kt[11];
#pragma unroll
        for (int u = 0; u < 11; ++u) kt[u] = tapsG[m0 + u];      // s_load
#pragma unroll
        for (int d = 0; d < 8; ++d) {                            // s desc = j asc
          const double xv = (double)xf[7 - d];
          a0 += kt[d + 0] * xv;
          a1 += kt[d + 1] * xv;
          a2 += kt[d + 2] * xv;
          a3 += kt[d + 3] * xv;
        }
      }
      float* ub = ubuf + bufsel * (QMAX * 64) + (t0 - qs) * 64 + lane;
      ub[0]   = (float)a0;
      ub[64]  = (float)a1;
      ub[128] = (float)a2;
      ub[192] = (float)a3;
    }
  };

  float RX = 0.0f, RY = 0.0f;
  unsigned long long* maskW = maskG + (size_t)b * (5 * TLEN) + bh * TLEN;

  // scan one quarter (wave 0 only; exact-f32 order as verified R2-R7)
  auto scan_range = [&](int qs, int qlen, int bufsel) {
    const float* ub = ubuf + bufsel * (QMAX * 64) + lane;
#pragma clang loop unroll(disable)
    for (int r = 0; r < qlen; r += 4) {
      float u0 = ub[(r + 0) * 64];
      float u1 = ub[(r + 1) * 64];
      float u2 = ub[(r + 2) * 64];
      float u3 = ub[(r + 3) * 64];
#pragma unroll
      for (int d = 0; d < 4; ++d) {
        float umem = (d == 0) ? u0 : (d == 1) ? u1 : (d == 2) ? u2 : u3;
        float v  = __fsub_rn(__fadd_rn(umem, RX), THETA);
        bool  sp = (v >= 0.0f) && (h < HID);
        unsigned long long bal = __ballot(sp);
        if (lane == 0) maskW[qs + r + d] = bal;
        float sf = sp ? 1.0f : 0.0f;
        float y2 = __fadd_rn(RY, __fmul_rn(Af, sf));
        RX = __fmul_rn(arf, __fadd_rn(RX, y2));
        RY = __fmul_rn(arf, y2);
      }
    }
  };

  // ---- quarter pipeline: scan(q) || fir(q+1) ----
  const int qs_[5] = {0, 76, 152, 228, 300};
  fir_range(0, 76, 0, wv, 16);            // all 16 waves
  __syncthreads();
#pragma clang loop unroll(disable)
  for (int q = 0; q < 4; ++q) {
    if (wv == 0) {
      scan_range(qs_[q], qs_[q + 1] - qs_[q], q & 1);
    } else if (q < 3) {
      fir_range(qs_[q + 1], qs_[q + 2] - qs_[q + 1], (q + 1) & 1, wv - 1, 15);
    }
    __syncthreads();
  }
}

// ================== Kernel 2: layer-2 + head (per b) ======================
__global__ __launch_bounds__(320)
void snn_l2_kernel(const float* __restrict__ W2,
                   const unsigned long long* __restrict__ maskG,
                   float* __restrict__ out) {
  __shared__ double             kD[100];
  __shared__ double             W2D[2 * HID];
  __shared__ unsigned long long maskL[5 * TLEN];   // [5][300]
  __shared__ double             zD[2 * 304];
  __shared__ float              u2L[2 * 304];
  __shared__ float              lgL[2];

  const int tid = threadIdx.x;
  const int b   = blockIdx.x;

  const float arf = (float)0.6065306597126334;
  const float Af  = (float)-27.182818284590452;

  for (int j = tid; j < 100; j += 320) {
    float q  = (float)j / 10.0f;
    float ef = (float)exp((double)(1.0f - q));
    kD[j] = (double)__fmul_rn(q, ef);
  }
  for (int i = tid; i < 2 * HID; i += 320)
    W2D[i] = (double)W2[i];
  for (int i = tid; i < 5 * TLEN; i += 320)
    maskL[i] = maskG[(size_t)b * (5 * TLEN) + i];
  __syncthreads();

  // ---- fc2: flat ascending-h f64 chain, branchless (bit-identical) ----
  if (tid < TLEN) {
    const int t = tid;
    double z0 = 0.0, z1 = 0.0;
#pragma unroll
    for (int w5 = 0; w5 < 5; ++w5) {
      const unsigned long long mm = maskL[w5 * TLEN + t];
      const int kend = (w5 == 4) ? (HID - 256) : 64;
      for (int k = 0; k < kend; ++k) {
        const bool bit = (mm >> k) & 1ull;
        const int  hh  = w5 * 64 + k;
        z0 += bit ? W2D[hh] : 0.0;
        z1 += bit ? W2D[HID + hh] : 0.0;
      }
    }
    zD[t]       = (double)((float)z0);   // f32-rounded at tensor boundary
    zD[304 + t] = (double)((float)z1);
  }
  __syncthreads();

  // ---- psp2 (f64 accumulate, j ascending) ----
  if (tid < TLEN) {
    const int t = tid;
    double a0 = 0.0, a1 = 0.0;
    const int jmax = (t < KTAP) ? t : KTAP;
    for (int j = 1; j <= jmax; ++j) {
      const double kk = kD[j];
      a0 += kk * zD[t - j];
      a1 += kk * zD[304 + t - j];
    }
    u2L[t]       = (float)a0;
    u2L[304 + t] = (float)a1;
  }
  __syncthreads();

  // ---- layer-2 spike scan + count ----
  if (tid < 2) {
    float RX = 0.0f, RY = 0.0f;
    int cnt = 0;
    for (int t = 0; t < TLEN; ++t) {
      float u  = u2L[tid * 304 + t];
      float v  = __fsub_rn(__fadd_rn(u, RX), THETA);
      bool  sp = (v >= 0.0f);
      cnt += sp ? 1 : 0;
      float sf = sp ? 1.0f : 0.0f;
      float y2 = __fadd_rn(RY, __fmul_rn(Af, sf));
      RX = __fmul_rn(arf, __fadd_rn(RX, y2));
      RY = __fmul_rn(arf, y2);
    }
    lgL[tid] = (float)cnt;
  }
  __syncthreads();

  // ---- head (verified) ----
  if (tid == 0) {
    float l0 = lgL[0], l1 = lgL[1];
    uint32_t o0, o1;
    threefry2x32(0u, 2u * (uint32_t)b, o0, o1);
    float g0 = -logf(-logf(jax_uniform_from_bits(o0 ^ o1)));
    threefry2x32(0u, 2u * (uint32_t)b + 1u, o0, o1);
    float g1 = -logf(-logf(jax_uniform_from_bits(o0 ^ o1)));

    float v0 = __fadd_rn(l0, g0);
    float v1 = __fadd_rn(l1, g1);
    int   pi = (v1 > v0) ? 1 : 0;
    float m   = fmaxf(l0, l1);
    float s0f = __fsub_rn(l0, m), s1f = __fsub_rn(l1, m);
    float lse = logf(__fadd_rn(expf(s0f), expf(s1f)));
    float lp  = __fsub_rn(pi ? s1f : s0f, lse);

    out[2 * b + 0] = l0;
    out[2 * b + 1] = l1;
    out[2048 + b]  = (float)pi;
    out[3072 + b]  = lp;
  }
}

extern "C" void kernel_launch(void* const* d_in, const int* in_sizes, int n_in,
                              void* d_out, int out_size, void* d_ws, size_t ws_size,
                              hipStream_t stream) {
  const float* enc = (const float*)d_in[0];
  const float* W1  = (const float*)d_in[1];
  const float* W2  = (const float*)d_in[2];
  float* out = (float*)d_out;

  double*             tapsG = (double*)d_ws;                          // 856 B
  unsigned long long* maskG = (unsigned long long*)((char*)d_ws + 1024);  // 12.3 MB

  hipFuncSetAttribute((const void*)snn_l1_kernel,
                      hipFuncAttributeMaxDynamicSharedMemorySize, LDS_K1);

  snn_taps_kernel<<<dim3(1), dim3(128), 0, stream>>>(tapsG);
  snn_l1_kernel<<<dim3(5, NB), dim3(1024), LDS_K1, stream>>>(enc, W1, tapsG, maskG);
  snn_l2_kernel<<<dim3(NB), dim3(320), 0, stream>>>(W2, maskG, out);
}